// Round 12
// baseline (266.677 us; speedup 1.0000x reference)
//
#include <hip/hip_runtime.h>

#define N_NODES 50000
#define N_EDGES 800000
#define NFEAT 128
#define NHID 128
#define NCLASS 10
#define NUM_GRAPHS 512
#define GEMM_BLOCKS 391    // ceil(50000/128), 128-row tiles
#define SLOT 64            // per-node CSR capacity; 64*2B = one 128B line
#define NBUK 391           // ceil(50000/128) radix buckets (bk = d>>7)
#define ECAP 512           // per-(bucket,xcd) stream capacity

typedef __attribute__((ext_vector_type(8))) short bf16x8;
typedef __attribute__((ext_vector_type(4))) float f32x4;

__device__ inline ushort f2bf(float f) {
  union { float f; uint u; } c; c.f = f;
  return (ushort)((c.u + 0x7fffu + ((c.u >> 16) & 1u)) >> 16);
}
__device__ inline float bf2f_lo(uint u) { union { uint u; float f; } c; c.u = u << 16; return c.f; }
__device__ inline float bf2f_hi(uint u) { union { uint u; float f; } c; c.u = u & 0xffff0000u; return c.f; }
__device__ inline float bf2f_s(ushort h) { union { uint u; float f; } c; c.u = ((uint)h) << 16; return c.f; }

// ---------------- MFMA GEMM: 128-row tile, 512 threads (8 waves), 64KB LDS ----------
// 2 blocks/CU -> all 391 blocks resident in one generation (latency amortized).
template <bool XFP32>
__device__ inline void gemm_body(const void* __restrict__ Xv,
                                 const ushort* __restrict__ Wp,
                                 ushort* __restrict__ Y,
                                 ushort* xs, ushort* wsh,
                                 int base, int tid) {
  const int rem = N_NODES - base;
  for (int i = tid; i < 2048; i += 512)
    ((uint4*)wsh)[i] = ((const uint4*)Wp)[i];

  // stage X tile (128 rows) as packed A-fragments: [wt 0..7][ks 0..3][lane][8]
  for (int g = tid; g < 2048; g += 512) {
    int row = g >> 4;            // 0..127
    int k0 = (g & 15) << 3;
    int wt = row >> 4, ks = k0 >> 5;
    int lane = (row & 15) + (((k0 >> 3) & 3) << 4);
    uint4 v;
    if (row < rem) {
      if (XFP32) {
        const float* s = (const float*)Xv + (size_t)(base + row) * 128 + k0;
        float4 p0 = ((const float4*)s)[0];
        float4 p1 = ((const float4*)s)[1];
        v.x = (uint)f2bf(p0.x) | ((uint)f2bf(p0.y) << 16);
        v.y = (uint)f2bf(p0.z) | ((uint)f2bf(p0.w) << 16);
        v.z = (uint)f2bf(p1.x) | ((uint)f2bf(p1.y) << 16);
        v.w = (uint)f2bf(p1.z) | ((uint)f2bf(p1.w) << 16);
      } else {
        v = *(const uint4*)((const ushort*)Xv + (size_t)(base + row) * 128 + k0);
      }
    } else {
      v.x = 0; v.y = 0; v.z = 0; v.w = 0;
    }
    *(uint4*)&xs[((((wt << 2) + ks) << 6) + lane) << 3] = v;
  }
  __syncthreads();

  const int wave = tid >> 6, lane = tid & 63;
  f32x4 acc[8];
#pragma unroll
  for (int i = 0; i < 8; ++i) acc[i] = f32x4{0.f, 0.f, 0.f, 0.f};
  bf16x8 a[4];
#pragma unroll
  for (int ks = 0; ks < 4; ++ks)
    a[ks] = *(const bf16x8*)&xs[((((wave << 2) + ks) << 6) + lane) << 3];
#pragma unroll
  for (int ks = 0; ks < 4; ++ks) {
#pragma unroll
    for (int nt = 0; nt < 8; ++nt) {
      bf16x8 b = *(const bf16x8*)&wsh[((((nt << 2) + ks) << 6) + lane) << 3];
      acc[nt] = __builtin_amdgcn_mfma_f32_16x16x32_bf16(a[ks], b, acc[nt], 0, 0, 0);
    }
  }
  // C/D: col = lane&15, row = (lane>>4)*4 + reg
  const int r0 = base + wave * 16 + ((lane >> 4) << 2);
  const int c0 = lane & 15;
#pragma unroll
  for (int nt = 0; nt < 8; ++nt)
#pragma unroll
    for (int r = 0; r < 4; ++r) {
      int row = r0 + r;
      if (row < N_NODES)
        Y[(size_t)row * 128 + (nt << 4) + c0] = f2bf(acc[nt][r]);
    }
}

__global__ __launch_bounds__(512) void k_gemm1(const float* __restrict__ X,
                                               const ushort* __restrict__ Wp,
                                               ushort* __restrict__ Y) {
  __shared__ ushort xs[8 * 4 * 64 * 8];   // 32 KB
  __shared__ ushort wsh[32 * 64 * 8];     // 32 KB
  gemm_body<true>(X, Wp, Y, xs, wsh, blockIdx.x * 128, threadIdx.x);
}

__global__ __launch_bounds__(512) void k_gemm2(const ushort* __restrict__ X,
                                               const ushort* __restrict__ Wp,
                                               ushort* __restrict__ Y) {
  __shared__ ushort xs[8 * 4 * 64 * 8];
  __shared__ ushort wsh[32 * 64 * 8];
  gemm_body<false>(X, Wp, Y, xs, wsh, blockIdx.x * 128, threadIdx.x);
}

// ---------------- W pre-pack (both weights; 128 blocks) ----------------
__global__ __launch_bounds__(256) void k_wpack(const float* __restrict__ W1,
                                               const float* __restrict__ W2,
                                               ushort* __restrict__ wp1,
                                               ushort* __restrict__ wp2) {
  int idx = blockIdx.x * 256 + threadIdx.x;  // 0..32767
  const float* W = (idx < 16384) ? W1 : W2;
  ushort* op = (idx < 16384) ? wp1 : wp2;
  int j = idx & 16383;
  int lane = (j >> 3) & 63;
  int e = j & 7;
  int frag = j >> 9;
  int nt = frag >> 2, ks = frag & 3;
  int c = nt * 16 + (lane & 15);
  int k = ks * 32 + (lane >> 4) * 8 + e;
  op[j] = f2bf(W[k * 128 + c]);
}

// ---------------- phase-1 radix edge scatter (standalone, no LDS) ----------------
// bucket = dst>>7; edge packed as src|dloc<<16; appended to per-(bucket, physical
// XCD) stream so each 64B stream line is dirtied by one L2 only.
__global__ __launch_bounds__(256) void k_scat(const int* __restrict__ esrc,
                                              const int* __restrict__ edst,
                                              int* __restrict__ cnt8,
                                              uint* __restrict__ ebuf) {
  uint xcc;
  asm volatile("s_getreg_b32 %0, hwreg(HW_REG_XCC_ID)" : "=s"(xcc));
  const int x = (int)(xcc & 7);
  for (int e = blockIdx.x * 256 + threadIdx.x; e < N_EDGES; e += gridDim.x * 256) {
    int d = edst[e];
    int bk = d >> 7;
    int dloc = d & 127;
    int p = atomicAdd(&cnt8[(bk << 3) + x], 1);
    if (p < ECAP)
      ebuf[(((size_t)bk << 3) + x) * ECAP + p] = (uint)esrc[e] | ((uint)dloc << 16);
  }
}

// ---------------- phase 2: per-bucket slot-CSR assembly in LDS ----------------
__global__ __launch_bounds__(256) void k_csr(const uint* __restrict__ ebuf,
                                             const int* __restrict__ cnt8,
                                             ushort* __restrict__ csr16,
                                             int* __restrict__ cnt) {
  __shared__ ushort csr_l[4096];
  __shared__ int cntL[128], off[128], cur[128];
  __shared__ int len8[8];
  const int b = blockIdx.x, tid = threadIdx.x;
  const int n0 = b << 7;
  const int nmax = min(128, N_NODES - n0);
  if (tid < 8) len8[tid] = min(cnt8[(b << 3) + tid], ECAP);
  for (int i = tid; i < 128; i += 256) { cntL[i] = 0; cur[i] = 0; }
  __syncthreads();
#pragma unroll
  for (int x = 0; x < 8; ++x) {
    const uint* s = ebuf + (((size_t)b << 3) + x) * ECAP;
    for (int i = tid; i < len8[x]; i += 256)
      atomicAdd(&cntL[s[i] >> 16], 1);
  }
  __syncthreads();
  if (tid == 0) {
    int o = 0;
    for (int n = 0; n < 128; ++n) { off[n] = o; o += min(cntL[n], SLOT); }
  }
  __syncthreads();
#pragma unroll
  for (int x = 0; x < 8; ++x) {
    const uint* s = ebuf + (((size_t)b << 3) + x) * ECAP;
    for (int i = tid; i < len8[x]; i += 256) {
      uint u = s[i];
      int dl = u >> 16;
      int p = atomicAdd(&cur[dl], 1);
      if (p < SLOT) csr_l[off[dl] + p] = (ushort)(u & 0xffffu);
    }
  }
  __syncthreads();
  for (int n = tid; n < nmax; n += 256) cnt[n0 + n] = min(cntL[n], SLOT);
  uint* outp = (uint*)csr16 + ((size_t)n0 << 5);
  const int tot = nmax << 5;
  for (int j = tid; j < tot; j += 256) {
    int n = j >> 5, k = (j & 31) << 1;
    int c = min(cntL[n], SLOT);
    uint lo = (k < c) ? (uint)csr_l[off[n] + k] : 0u;
    uint hi = (k + 1 < c) ? (uint)csr_l[off[n] + k + 1] : 0u;
    outp[((size_t)n << 5) + (j & 31)] = lo | (hi << 16);
  }
}

// ---------------- quarter-wave gather: 16 lanes x uint4 = one 256B row ----------------
__device__ inline void unpack_add(uint4 u, float4& a0, float4& a1) {
  a0.x += bf2f_lo(u.x); a0.y += bf2f_hi(u.x);
  a0.z += bf2f_lo(u.y); a0.w += bf2f_hi(u.y);
  a1.x += bf2f_lo(u.z); a1.y += bf2f_hi(u.z);
  a1.z += bf2f_lo(u.w); a1.w += bf2f_hi(u.w);
}

__device__ inline void gather_sum(const uint4* __restrict__ Hv,
                                  const ushort* __restrict__ nb,
                                  int deg, int q, float4& a0, float4& a1) {
  int e = 0;
  for (; e + 8 <= deg; e += 8) {
    uint4 iv = *(const uint4*)(nb + e);
    uint4 u0 = Hv[(size_t)(iv.x & 0xffffu) * 16 + q];
    uint4 u1 = Hv[(size_t)(iv.x >> 16) * 16 + q];
    uint4 u2 = Hv[(size_t)(iv.y & 0xffffu) * 16 + q];
    uint4 u3 = Hv[(size_t)(iv.y >> 16) * 16 + q];
    uint4 u4 = Hv[(size_t)(iv.z & 0xffffu) * 16 + q];
    uint4 u5 = Hv[(size_t)(iv.z >> 16) * 16 + q];
    uint4 u6 = Hv[(size_t)(iv.w & 0xffffu) * 16 + q];
    uint4 u7 = Hv[(size_t)(iv.w >> 16) * 16 + q];
    unpack_add(u0, a0, a1); unpack_add(u1, a0, a1);
    unpack_add(u2, a0, a1); unpack_add(u3, a0, a1);
    unpack_add(u4, a0, a1); unpack_add(u5, a0, a1);
    unpack_add(u6, a0, a1); unpack_add(u7, a0, a1);
  }
  if (e + 4 <= deg) {
    uint2 iv = *(const uint2*)(nb + e);
    uint4 u0 = Hv[(size_t)(iv.x & 0xffffu) * 16 + q];
    uint4 u1 = Hv[(size_t)(iv.x >> 16) * 16 + q];
    uint4 u2 = Hv[(size_t)(iv.y & 0xffffu) * 16 + q];
    uint4 u3 = Hv[(size_t)(iv.y >> 16) * 16 + q];
    unpack_add(u0, a0, a1); unpack_add(u1, a0, a1);
    unpack_add(u2, a0, a1); unpack_add(u3, a0, a1);
    e += 4;
  }
  for (; e < deg; ++e) {
    uint4 u = Hv[(size_t)nb[e] * 16 + q];
    unpack_add(u, a0, a1);
  }
}

// ---------------- agg layer1: 16 nodes/block (4 waves x 4 quarter-waves) -------------
__global__ __launch_bounds__(256) void k_agg1(const ushort* __restrict__ H,
                                              const ushort* __restrict__ csr16,
                                              const int* __restrict__ cnt,
                                              ushort* __restrict__ Out) {
  const int q = threadIdx.x & 15;
  const int node = blockIdx.x * 16 + (threadIdx.x >> 4);  // 50000 = 3125*16 exact
  const int deg = min(cnt[node], SLOT);
  const ushort* nb = csr16 + (size_t)node * SLOT;
  const uint4* __restrict__ Hv = (const uint4*)H;
  float4 a0 = {0.f, 0.f, 0.f, 0.f}, a1 = {0.f, 0.f, 0.f, 0.f};
  gather_sum(Hv, nb, deg, q, a0, a1);
  uint4 uh = Hv[(size_t)node * 16 + q];
  float inv = 1.0f / (float)(deg + 1);
  float v0 = fmaxf((bf2f_lo(uh.x) + a0.x) * inv, 0.f);
  float v1 = fmaxf((bf2f_hi(uh.x) + a0.y) * inv, 0.f);
  float v2 = fmaxf((bf2f_lo(uh.y) + a0.z) * inv, 0.f);
  float v3 = fmaxf((bf2f_hi(uh.y) + a0.w) * inv, 0.f);
  float v4 = fmaxf((bf2f_lo(uh.z) + a1.x) * inv, 0.f);
  float v5 = fmaxf((bf2f_hi(uh.z) + a1.y) * inv, 0.f);
  float v6 = fmaxf((bf2f_lo(uh.w) + a1.z) * inv, 0.f);
  float v7 = fmaxf((bf2f_hi(uh.w) + a1.w) * inv, 0.f);
  uint4 ov;
  ov.x = (uint)f2bf(v0) | ((uint)f2bf(v1) << 16);
  ov.y = (uint)f2bf(v2) | ((uint)f2bf(v3) << 16);
  ov.z = (uint)f2bf(v4) | ((uint)f2bf(v5) << 16);
  ov.w = (uint)f2bf(v6) | ((uint)f2bf(v7) << 16);
  ((uint4*)Out)[(size_t)node * 16 + q] = ov;
}

// ---------------- fused agg2 + per-graph readout (gid sorted) ----------------
__global__ __launch_bounds__(256) void k_agg_ro(const ushort* __restrict__ H,
                                                const ushort* __restrict__ csr16,
                                                const int* __restrict__ cnt,
                                                const int* __restrict__ gid,
                                                float* __restrict__ gsum,
                                                float* __restrict__ gcnt) {
  __shared__ float rows[16][128];
  __shared__ int gids[16];
  const int q = threadIdx.x & 15;
  const int slot = threadIdx.x >> 4;
  const int node = blockIdx.x * 16 + slot;  // exact
  const int deg = min(cnt[node], SLOT);
  const ushort* nb = csr16 + (size_t)node * SLOT;
  const uint4* __restrict__ Hv = (const uint4*)H;
  float4 a0 = {0.f, 0.f, 0.f, 0.f}, a1 = {0.f, 0.f, 0.f, 0.f};
  gather_sum(Hv, nb, deg, q, a0, a1);
  uint4 uh = Hv[(size_t)node * 16 + q];
  float inv = 1.0f / (float)(deg + 1);
  float4 r0, r1;
  r0.x = bf2f_s(f2bf((bf2f_lo(uh.x) + a0.x) * inv));
  r0.y = bf2f_s(f2bf((bf2f_hi(uh.x) + a0.y) * inv));
  r0.z = bf2f_s(f2bf((bf2f_lo(uh.y) + a0.z) * inv));
  r0.w = bf2f_s(f2bf((bf2f_hi(uh.y) + a0.w) * inv));
  r1.x = bf2f_s(f2bf((bf2f_lo(uh.z) + a1.x) * inv));
  r1.y = bf2f_s(f2bf((bf2f_hi(uh.z) + a1.y) * inv));
  r1.z = bf2f_s(f2bf((bf2f_lo(uh.w) + a1.z) * inv));
  r1.w = bf2f_s(f2bf((bf2f_hi(uh.w) + a1.w) * inv));
  *(float4*)&rows[slot][q * 8] = r0;
  *(float4*)&rows[slot][q * 8 + 4] = r1;
  if (q == 0) gids[slot] = gid[node];
  __syncthreads();
  const int t = threadIdx.x;
  if (t < 128) {
    float acc = rows[0][t];
    int g = gids[0];
#pragma unroll
    for (int r = 1; r < 16; ++r) {
      int gr = gids[r];
      if (gr != g) {
        atomicAdd(&gsum[g * 128 + t], acc);
        acc = 0.f;
        g = gr;
      }
      acc += rows[r][t];
    }
    atomicAdd(&gsum[g * 128 + t], acc);
  } else if (t == 128) {
    float c = 1.f;
    int g = gids[0];
#pragma unroll
    for (int r = 1; r < 16; ++r) {
      int gr = gids[r];
      if (gr != g) {
        atomicAdd(&gcnt[g], c);
        c = 0.f;
        g = gr;
      }
      c += 1.f;
    }
    atomicAdd(&gcnt[g], c);
  }
}

// ---------------- gmean @ mlp_w + b, log_softmax ----------------
__global__ __launch_bounds__(128) void k_mlp(const float* __restrict__ gsum,
                                             const float* __restrict__ gcnt,
                                             const float* __restrict__ Wm,
                                             const float* __restrict__ bm,
                                             float* __restrict__ out) {
  __shared__ float m[128];
  __shared__ float lg[NCLASS];
  const int g = blockIdx.x;
  const int t = threadIdx.x;
  float cnt = fmaxf(gcnt[g], 1.0f);
  m[t] = gsum[g * 128 + t] / cnt;
  __syncthreads();
  if (t < NCLASS) {
    float s = bm[t];
#pragma unroll
    for (int k = 0; k < 128; ++k) s += m[k] * Wm[k * NCLASS + t];
    lg[t] = s;
  }
  __syncthreads();
  if (t < NCLASS) {
    float mx = lg[0];
#pragma unroll
    for (int i = 1; i < NCLASS; ++i) mx = fmaxf(mx, lg[i]);
    float sum = 0.f;
#pragma unroll
    for (int i = 0; i < NCLASS; ++i) sum += expf(lg[i] - mx);
    out[g * NCLASS + t] = lg[t] - mx - logf(sum);
  }
}

extern "C" void kernel_launch(void* const* d_in, const int* in_sizes, int n_in,
                              void* d_out, int out_size, void* d_ws, size_t ws_size,
                              hipStream_t stream) {
  const float* feat = (const float*)d_in[0];
  const float* W1   = (const float*)d_in[1];
  const float* W2   = (const float*)d_in[2];
  const float* Wm   = (const float*)d_in[3];
  const float* bm   = (const float*)d_in[4];
  const int* esrc   = (const int*)d_in[5];
  const int* edst   = (const int*)d_in[6];
  const int* gid    = (const int*)d_in[7];
  float* out = (float*)d_out;

  // workspace layout:
  // ints:   cnt8[3200] | cnt[50048]
  // uint:   ebuf[391*8*512]  (6.4 MB)
  // ushort: csr16[50048*64] | wp1[16384] | wp2[16384] | bufA[6.4M] | bufB[6.4M]
  // float:  gsum[512*128] | gcnt[512]
  int* cnt8     = (int*)d_ws;
  int* cnt      = cnt8 + 3200;
  uint* ebuf    = (uint*)(cnt + 50048);
  ushort* csr16 = (ushort*)(ebuf + (size_t)NBUK * 8 * ECAP);
  ushort* wp1   = csr16 + (size_t)50048 * SLOT;
  ushort* wp2   = wp1 + 16384;
  ushort* bufA  = wp2 + 16384;
  ushort* bufB  = bufA + (size_t)N_NODES * NHID;
  float* gsum   = (float*)(bufB + (size_t)N_NODES * NHID);
  float* gcnt   = gsum + NUM_GRAPHS * NHID;

  hipMemsetAsync(cnt8, 0, (size_t)3200 * sizeof(int), stream);
  hipMemsetAsync(gsum, 0, (size_t)(NUM_GRAPHS * NHID + 512) * sizeof(float), stream);

  k_wpack<<<128, 256, 0, stream>>>(W1, W2, wp1, wp2);
  k_scat<<<1024, 256, 0, stream>>>(esrc, edst, cnt8, ebuf);
  k_csr<<<NBUK, 256, 0, stream>>>(ebuf, cnt8, csr16, cnt);

  // h1 = feat@W1 -> bufA (bf16)
  k_gemm1<<<GEMM_BLOCKS, 512, 0, stream>>>(feat, wp1, bufA);
  // x1 = relu((h1+gather)/deg) -> bufB
  k_agg1<<<N_NODES / 16, 256, 0, stream>>>(bufA, csr16, cnt, bufB);
  // h2 = x1@W2 -> bufA
  k_gemm2<<<GEMM_BLOCKS, 512, 0, stream>>>(bufB, wp2, bufA);
  // x2 = (h2+gather)/deg fused with per-graph sum readout
  k_agg_ro<<<N_NODES / 16, 256, 0, stream>>>(bufA, csr16, cnt, gid, gsum, gcnt);

  k_mlp<<<NUM_GRAPHS, 128, 0, stream>>>(gsum, gcnt, Wm, bm, out);
}

// Round 13
// 230.001 us; speedup vs baseline: 1.1595x; 1.1595x over previous
//
#include <hip/hip_runtime.h>

#define N_NODES 50000
#define N_EDGES 800000
#define NFEAT 128
#define NHID 128
#define NCLASS 10
#define NUM_GRAPHS 512
#define GEMM_BLOCKS 391    // ceil(50000/128), 128-row tiles
#define SLOT 64            // per-node CSR capacity; 64*2B = one 128B line
#define NBUK 391           // ceil(50000/128) radix buckets (bk = d>>7)
#define ECAP 512           // per-(bucket,xcd) stream capacity
#define CPAD 32            // ints per counter: one 128B line each (atomic units serialize per line)

typedef __attribute__((ext_vector_type(8))) short bf16x8;
typedef __attribute__((ext_vector_type(4))) float f32x4;

__device__ inline ushort f2bf(float f) {
  union { float f; uint u; } c; c.f = f;
  return (ushort)((c.u + 0x7fffu + ((c.u >> 16) & 1u)) >> 16);
}
__device__ inline float bf2f_lo(uint u) { union { uint u; float f; } c; c.u = u << 16; return c.f; }
__device__ inline float bf2f_hi(uint u) { union { uint u; float f; } c; c.u = u & 0xffff0000u; return c.f; }
__device__ inline float bf2f_s(ushort h) { union { uint u; float f; } c; c.u = ((uint)h) << 16; return c.f; }

// ---------------- MFMA GEMM: 128-row tile, 512 threads (8 waves), 64KB LDS ----------
template <bool XFP32>
__device__ inline void gemm_body(const void* __restrict__ Xv,
                                 const ushort* __restrict__ Wp,
                                 ushort* __restrict__ Y,
                                 ushort* xs, ushort* wsh,
                                 int base, int tid) {
  const int rem = N_NODES - base;
  for (int i = tid; i < 2048; i += 512)
    ((uint4*)wsh)[i] = ((const uint4*)Wp)[i];

  for (int g = tid; g < 2048; g += 512) {
    int row = g >> 4;            // 0..127
    int k0 = (g & 15) << 3;
    int wt = row >> 4, ks = k0 >> 5;
    int lane = (row & 15) + (((k0 >> 3) & 3) << 4);
    uint4 v;
    if (row < rem) {
      if (XFP32) {
        const float* s = (const float*)Xv + (size_t)(base + row) * 128 + k0;
        float4 p0 = ((const float4*)s)[0];
        float4 p1 = ((const float4*)s)[1];
        v.x = (uint)f2bf(p0.x) | ((uint)f2bf(p0.y) << 16);
        v.y = (uint)f2bf(p0.z) | ((uint)f2bf(p0.w) << 16);
        v.z = (uint)f2bf(p1.x) | ((uint)f2bf(p1.y) << 16);
        v.w = (uint)f2bf(p1.z) | ((uint)f2bf(p1.w) << 16);
      } else {
        v = *(const uint4*)((const ushort*)Xv + (size_t)(base + row) * 128 + k0);
      }
    } else {
      v.x = 0; v.y = 0; v.z = 0; v.w = 0;
    }
    *(uint4*)&xs[((((wt << 2) + ks) << 6) + lane) << 3] = v;
  }
  __syncthreads();

  const int wave = tid >> 6, lane = tid & 63;
  f32x4 acc[8];
#pragma unroll
  for (int i = 0; i < 8; ++i) acc[i] = f32x4{0.f, 0.f, 0.f, 0.f};
  bf16x8 a[4];
#pragma unroll
  for (int ks = 0; ks < 4; ++ks)
    a[ks] = *(const bf16x8*)&xs[((((wave << 2) + ks) << 6) + lane) << 3];
#pragma unroll
  for (int ks = 0; ks < 4; ++ks) {
#pragma unroll
    for (int nt = 0; nt < 8; ++nt) {
      bf16x8 b = *(const bf16x8*)&wsh[((((nt << 2) + ks) << 6) + lane) << 3];
      acc[nt] = __builtin_amdgcn_mfma_f32_16x16x32_bf16(a[ks], b, acc[nt], 0, 0, 0);
    }
  }
  // C/D: col = lane&15, row = (lane>>4)*4 + reg
  const int r0 = base + wave * 16 + ((lane >> 4) << 2);
  const int c0 = lane & 15;
#pragma unroll
  for (int nt = 0; nt < 8; ++nt)
#pragma unroll
    for (int r = 0; r < 4; ++r) {
      int row = r0 + r;
      if (row < N_NODES)
        Y[(size_t)row * 128 + (nt << 4) + c0] = f2bf(acc[nt][r]);
    }
}

__global__ __launch_bounds__(512) void k_gemm1(const float* __restrict__ X,
                                               const ushort* __restrict__ Wp,
                                               ushort* __restrict__ Y) {
  __shared__ ushort xs[8 * 4 * 64 * 8];   // 32 KB
  __shared__ ushort wsh[32 * 64 * 8];     // 32 KB
  gemm_body<true>(X, Wp, Y, xs, wsh, blockIdx.x * 128, threadIdx.x);
}

__global__ __launch_bounds__(512) void k_gemm2(const ushort* __restrict__ X,
                                               const ushort* __restrict__ Wp,
                                               ushort* __restrict__ Y) {
  __shared__ ushort xs[8 * 4 * 64 * 8];
  __shared__ ushort wsh[32 * 64 * 8];
  gemm_body<false>(X, Wp, Y, xs, wsh, blockIdx.x * 128, threadIdx.x);
}

// ---------------- W pre-pack (both weights; 128 blocks) ----------------
__global__ __launch_bounds__(256) void k_wpack(const float* __restrict__ W1,
                                               const float* __restrict__ W2,
                                               ushort* __restrict__ wp1,
                                               ushort* __restrict__ wp2) {
  int idx = blockIdx.x * 256 + threadIdx.x;  // 0..32767
  const float* W = (idx < 16384) ? W1 : W2;
  ushort* op = (idx < 16384) ? wp1 : wp2;
  int j = idx & 16383;
  int lane = (j >> 3) & 63;
  int e = j & 7;
  int frag = j >> 9;
  int nt = frag >> 2, ks = frag & 3;
  int c = nt * 16 + (lane & 15);
  int k = ks * 32 + (lane >> 4) * 8 + e;
  op[j] = f2bf(W[k * 128 + c]);
}

// ---------------- phase-1 radix edge scatter ----------------
// bucket = dst>>7; edge packed as src|dloc<<16; appended to per-(bucket, physical
// XCD) stream. Counters are padded to one 128B line each: memory-side atomic
// units serialize per LINE, and dense counters cost 4080 serial ops/line (77us).
__global__ __launch_bounds__(256) void k_scat(const int* __restrict__ esrc,
                                              const int* __restrict__ edst,
                                              int* __restrict__ cnt8,
                                              uint* __restrict__ ebuf) {
  uint xcc;
  asm volatile("s_getreg_b32 %0, hwreg(HW_REG_XCC_ID)" : "=s"(xcc));
  const int x = (int)(xcc & 7);
  for (int e = blockIdx.x * 256 + threadIdx.x; e < N_EDGES; e += gridDim.x * 256) {
    int d = edst[e];
    int bk = d >> 7;
    int dloc = d & 127;
    int p = atomicAdd(&cnt8[((bk << 3) + x) * CPAD], 1);
    if (p < ECAP)
      ebuf[(((size_t)bk << 3) + x) * ECAP + p] = (uint)esrc[e] | ((uint)dloc << 16);
  }
}

// ---------------- phase 2: per-bucket slot-CSR assembly in LDS ----------------
__global__ __launch_bounds__(256) void k_csr(const uint* __restrict__ ebuf,
                                             const int* __restrict__ cnt8,
                                             ushort* __restrict__ csr16,
                                             int* __restrict__ cnt) {
  __shared__ ushort csr_l[4096];
  __shared__ int cntL[128], off[128], cur[128];
  __shared__ int len8[8];
  const int b = blockIdx.x, tid = threadIdx.x;
  const int n0 = b << 7;
  const int nmax = min(128, N_NODES - n0);
  if (tid < 8) len8[tid] = min(cnt8[((b << 3) + tid) * CPAD], ECAP);
  for (int i = tid; i < 128; i += 256) { cntL[i] = 0; cur[i] = 0; }
  __syncthreads();
#pragma unroll
  for (int x = 0; x < 8; ++x) {
    const uint* s = ebuf + (((size_t)b << 3) + x) * ECAP;
    for (int i = tid; i < len8[x]; i += 256)
      atomicAdd(&cntL[s[i] >> 16], 1);
  }
  __syncthreads();
  if (tid == 0) {
    int o = 0;
    for (int n = 0; n < 128; ++n) { off[n] = o; o += min(cntL[n], SLOT); }
  }
  __syncthreads();
#pragma unroll
  for (int x = 0; x < 8; ++x) {
    const uint* s = ebuf + (((size_t)b << 3) + x) * ECAP;
    for (int i = tid; i < len8[x]; i += 256) {
      uint u = s[i];
      int dl = u >> 16;
      int p = atomicAdd(&cur[dl], 1);
      if (p < SLOT) csr_l[off[dl] + p] = (ushort)(u & 0xffffu);
    }
  }
  __syncthreads();
  for (int n = tid; n < nmax; n += 256) cnt[n0 + n] = min(cntL[n], SLOT);
  uint* outp = (uint*)csr16 + ((size_t)n0 << 5);
  const int tot = nmax << 5;
  for (int j = tid; j < tot; j += 256) {
    int n = j >> 5, k = (j & 31) << 1;
    int c = min(cntL[n], SLOT);
    uint lo = (k < c) ? (uint)csr_l[off[n] + k] : 0u;
    uint hi = (k + 1 < c) ? (uint)csr_l[off[n] + k + 1] : 0u;
    outp[((size_t)n << 5) + (j & 31)] = lo | (hi << 16);
  }
}

// ---------------- quarter-wave gather: 16 lanes x uint4 = one 256B row ----------------
__device__ inline void unpack_add(uint4 u, float4& a0, float4& a1) {
  a0.x += bf2f_lo(u.x); a0.y += bf2f_hi(u.x);
  a0.z += bf2f_lo(u.y); a0.w += bf2f_hi(u.y);
  a1.x += bf2f_lo(u.z); a1.y += bf2f_hi(u.z);
  a1.z += bf2f_lo(u.w); a1.w += bf2f_hi(u.w);
}

__device__ inline void gather_sum(const uint4* __restrict__ Hv,
                                  const ushort* __restrict__ nb,
                                  int deg, int q, float4& a0, float4& a1) {
  int e = 0;
  for (; e + 8 <= deg; e += 8) {
    uint4 iv = *(const uint4*)(nb + e);
    uint4 u0 = Hv[(size_t)(iv.x & 0xffffu) * 16 + q];
    uint4 u1 = Hv[(size_t)(iv.x >> 16) * 16 + q];
    uint4 u2 = Hv[(size_t)(iv.y & 0xffffu) * 16 + q];
    uint4 u3 = Hv[(size_t)(iv.y >> 16) * 16 + q];
    uint4 u4 = Hv[(size_t)(iv.z & 0xffffu) * 16 + q];
    uint4 u5 = Hv[(size_t)(iv.z >> 16) * 16 + q];
    uint4 u6 = Hv[(size_t)(iv.w & 0xffffu) * 16 + q];
    uint4 u7 = Hv[(size_t)(iv.w >> 16) * 16 + q];
    unpack_add(u0, a0, a1); unpack_add(u1, a0, a1);
    unpack_add(u2, a0, a1); unpack_add(u3, a0, a1);
    unpack_add(u4, a0, a1); unpack_add(u5, a0, a1);
    unpack_add(u6, a0, a1); unpack_add(u7, a0, a1);
  }
  if (e + 4 <= deg) {
    uint2 iv = *(const uint2*)(nb + e);
    uint4 u0 = Hv[(size_t)(iv.x & 0xffffu) * 16 + q];
    uint4 u1 = Hv[(size_t)(iv.x >> 16) * 16 + q];
    uint4 u2 = Hv[(size_t)(iv.y & 0xffffu) * 16 + q];
    uint4 u3 = Hv[(size_t)(iv.y >> 16) * 16 + q];
    unpack_add(u0, a0, a1); unpack_add(u1, a0, a1);
    unpack_add(u2, a0, a1); unpack_add(u3, a0, a1);
    e += 4;
  }
  for (; e < deg; ++e) {
    uint4 u = Hv[(size_t)nb[e] * 16 + q];
    unpack_add(u, a0, a1);
  }
}

// ---------------- agg layer1: 16 nodes/block (4 waves x 4 quarter-waves) -------------
__global__ __launch_bounds__(256) void k_agg1(const ushort* __restrict__ H,
                                              const ushort* __restrict__ csr16,
                                              const int* __restrict__ cnt,
                                              ushort* __restrict__ Out) {
  const int q = threadIdx.x & 15;
  const int node = blockIdx.x * 16 + (threadIdx.x >> 4);  // 50000 = 3125*16 exact
  const int deg = min(cnt[node], SLOT);
  const ushort* nb = csr16 + (size_t)node * SLOT;
  const uint4* __restrict__ Hv = (const uint4*)H;
  float4 a0 = {0.f, 0.f, 0.f, 0.f}, a1 = {0.f, 0.f, 0.f, 0.f};
  gather_sum(Hv, nb, deg, q, a0, a1);
  uint4 uh = Hv[(size_t)node * 16 + q];
  float inv = 1.0f / (float)(deg + 1);
  float v0 = fmaxf((bf2f_lo(uh.x) + a0.x) * inv, 0.f);
  float v1 = fmaxf((bf2f_hi(uh.x) + a0.y) * inv, 0.f);
  float v2 = fmaxf((bf2f_lo(uh.y) + a0.z) * inv, 0.f);
  float v3 = fmaxf((bf2f_hi(uh.y) + a0.w) * inv, 0.f);
  float v4 = fmaxf((bf2f_lo(uh.z) + a1.x) * inv, 0.f);
  float v5 = fmaxf((bf2f_hi(uh.z) + a1.y) * inv, 0.f);
  float v6 = fmaxf((bf2f_lo(uh.w) + a1.z) * inv, 0.f);
  float v7 = fmaxf((bf2f_hi(uh.w) + a1.w) * inv, 0.f);
  uint4 ov;
  ov.x = (uint)f2bf(v0) | ((uint)f2bf(v1) << 16);
  ov.y = (uint)f2bf(v2) | ((uint)f2bf(v3) << 16);
  ov.z = (uint)f2bf(v4) | ((uint)f2bf(v5) << 16);
  ov.w = (uint)f2bf(v6) | ((uint)f2bf(v7) << 16);
  ((uint4*)Out)[(size_t)node * 16 + q] = ov;
}

// ---------------- fused agg2 + per-graph readout (gid sorted) ----------------
__global__ __launch_bounds__(256) void k_agg_ro(const ushort* __restrict__ H,
                                                const ushort* __restrict__ csr16,
                                                const int* __restrict__ cnt,
                                                const int* __restrict__ gid,
                                                float* __restrict__ gsum,
                                                float* __restrict__ gcnt) {
  __shared__ float rows[16][128];
  __shared__ int gids[16];
  const int q = threadIdx.x & 15;
  const int slot = threadIdx.x >> 4;
  const int node = blockIdx.x * 16 + slot;  // exact
  const int deg = min(cnt[node], SLOT);
  const ushort* nb = csr16 + (size_t)node * SLOT;
  const uint4* __restrict__ Hv = (const uint4*)H;
  float4 a0 = {0.f, 0.f, 0.f, 0.f}, a1 = {0.f, 0.f, 0.f, 0.f};
  gather_sum(Hv, nb, deg, q, a0, a1);
  uint4 uh = Hv[(size_t)node * 16 + q];
  float inv = 1.0f / (float)(deg + 1);
  float4 r0, r1;
  r0.x = bf2f_s(f2bf((bf2f_lo(uh.x) + a0.x) * inv));
  r0.y = bf2f_s(f2bf((bf2f_hi(uh.x) + a0.y) * inv));
  r0.z = bf2f_s(f2bf((bf2f_lo(uh.y) + a0.z) * inv));
  r0.w = bf2f_s(f2bf((bf2f_hi(uh.y) + a0.w) * inv));
  r1.x = bf2f_s(f2bf((bf2f_lo(uh.z) + a1.x) * inv));
  r1.y = bf2f_s(f2bf((bf2f_hi(uh.z) + a1.y) * inv));
  r1.z = bf2f_s(f2bf((bf2f_lo(uh.w) + a1.z) * inv));
  r1.w = bf2f_s(f2bf((bf2f_hi(uh.w) + a1.w) * inv));
  *(float4*)&rows[slot][q * 8] = r0;
  *(float4*)&rows[slot][q * 8 + 4] = r1;
  if (q == 0) gids[slot] = gid[node];
  __syncthreads();
  const int t = threadIdx.x;
  if (t < 128) {
    float acc = rows[0][t];
    int g = gids[0];
#pragma unroll
    for (int r = 1; r < 16; ++r) {
      int gr = gids[r];
      if (gr != g) {
        atomicAdd(&gsum[g * 128 + t], acc);
        acc = 0.f;
        g = gr;
      }
      acc += rows[r][t];
    }
    atomicAdd(&gsum[g * 128 + t], acc);
  } else if (t == 128) {
    float c = 1.f;
    int g = gids[0];
#pragma unroll
    for (int r = 1; r < 16; ++r) {
      int gr = gids[r];
      if (gr != g) {
        atomicAdd(&gcnt[g], c);
        c = 0.f;
        g = gr;
      }
      c += 1.f;
    }
    atomicAdd(&gcnt[g], c);
  }
}

// ---------------- gmean @ mlp_w + b, log_softmax ----------------
__global__ __launch_bounds__(128) void k_mlp(const float* __restrict__ gsum,
                                             const float* __restrict__ gcnt,
                                             const float* __restrict__ Wm,
                                             const float* __restrict__ bm,
                                             float* __restrict__ out) {
  __shared__ float m[128];
  __shared__ float lg[NCLASS];
  const int g = blockIdx.x;
  const int t = threadIdx.x;
  float cnt = fmaxf(gcnt[g], 1.0f);
  m[t] = gsum[g * 128 + t] / cnt;
  __syncthreads();
  if (t < NCLASS) {
    float s = bm[t];
#pragma unroll
    for (int k = 0; k < 128; ++k) s += m[k] * Wm[k * NCLASS + t];
    lg[t] = s;
  }
  __syncthreads();
  if (t < NCLASS) {
    float mx = lg[0];
#pragma unroll
    for (int i = 1; i < NCLASS; ++i) mx = fmaxf(mx, lg[i]);
    float sum = 0.f;
#pragma unroll
    for (int i = 0; i < NCLASS; ++i) sum += expf(lg[i] - mx);
    out[g * NCLASS + t] = lg[t] - mx - logf(sum);
  }
}

extern "C" void kernel_launch(void* const* d_in, const int* in_sizes, int n_in,
                              void* d_out, int out_size, void* d_ws, size_t ws_size,
                              hipStream_t stream) {
  const float* feat = (const float*)d_in[0];
  const float* W1   = (const float*)d_in[1];
  const float* W2   = (const float*)d_in[2];
  const float* Wm   = (const float*)d_in[3];
  const float* bm   = (const float*)d_in[4];
  const int* esrc   = (const int*)d_in[5];
  const int* edst   = (const int*)d_in[6];
  const int* gid    = (const int*)d_in[7];
  float* out = (float*)d_out;

  // workspace layout:
  // ints:   cnt8[3128*32 = 100096, line-padded] | cnt[50048]
  // uint:   ebuf[391*8*512]  (12.8 MB)
  // ushort: csr16[50048*64] | wp1[16384] | wp2[16384] | bufA[6.4M] | bufB[6.4M]
  // float:  gsum[512*128] | gcnt[512]
  int* cnt8     = (int*)d_ws;
  int* cnt      = cnt8 + NBUK * 8 * CPAD;
  uint* ebuf    = (uint*)(cnt + 50048);
  ushort* csr16 = (ushort*)(ebuf + (size_t)NBUK * 8 * ECAP);
  ushort* wp1   = csr16 + (size_t)50048 * SLOT;
  ushort* wp2   = wp1 + 16384;
  ushort* bufA  = wp2 + 16384;
  ushort* bufB  = bufA + (size_t)N_NODES * NHID;
  float* gsum   = (float*)(bufB + (size_t)N_NODES * NHID);
  float* gcnt   = gsum + NUM_GRAPHS * NHID;

  hipMemsetAsync(cnt8, 0, (size_t)NBUK * 8 * CPAD * sizeof(int), stream);
  hipMemsetAsync(gsum, 0, (size_t)(NUM_GRAPHS * NHID + 512) * sizeof(float), stream);

  k_wpack<<<128, 256, 0, stream>>>(W1, W2, wp1, wp2);
  k_scat<<<1024, 256, 0, stream>>>(esrc, edst, cnt8, ebuf);
  k_csr<<<NBUK, 256, 0, stream>>>(ebuf, cnt8, csr16, cnt);

  // h1 = feat@W1 -> bufA (bf16)
  k_gemm1<<<GEMM_BLOCKS, 512, 0, stream>>>(feat, wp1, bufA);
  // x1 = relu((h1+gather)/deg) -> bufB
  k_agg1<<<N_NODES / 16, 256, 0, stream>>>(bufA, csr16, cnt, bufB);
  // h2 = x1@W2 -> bufA
  k_gemm2<<<GEMM_BLOCKS, 512, 0, stream>>>(bufB, wp2, bufA);
  // x2 = (h2+gather)/deg fused with per-graph sum readout
  k_agg_ro<<<N_NODES / 16, 256, 0, stream>>>(bufA, csr16, cnt, gid, gsum, gcnt);

  k_mlp<<<NUM_GRAPHS, 128, 0, stream>>>(gsum, gcnt, Wm, bm, out);
}

// Round 14
// 225.555 us; speedup vs baseline: 1.1823x; 1.0197x over previous
//
#include <hip/hip_runtime.h>

#define N_NODES 50000
#define N_EDGES 800000
#define NFEAT 128
#define NHID 128
#define NCLASS 10
#define NUM_GRAPHS 512
#define GEMM_BLOCKS 391    // ceil(50000/128), 128-row tiles
#define SLOT 64            // per-node CSR capacity; 64*2B = one 128B line
#define NBUK 391           // ceil(50000/128) radix buckets (bk = d>>7)
#define ECAP 512           // per-(bucket,xcd) stream capacity
#define CPAD 32            // ints per counter: one 128B line each

typedef __attribute__((ext_vector_type(8))) short bf16x8;
typedef __attribute__((ext_vector_type(4))) float f32x4;

__device__ inline ushort f2bf(float f) {
  union { float f; uint u; } c; c.f = f;
  return (ushort)((c.u + 0x7fffu + ((c.u >> 16) & 1u)) >> 16);
}
__device__ inline float bf2f_lo(uint u) { union { uint u; float f; } c; c.u = u << 16; return c.f; }
__device__ inline float bf2f_hi(uint u) { union { uint u; float f; } c; c.u = u & 0xffff0000u; return c.f; }

// ---------------- MFMA GEMM: 128-row tile, 512 threads, bf16 in, optional ReLU ------
template <bool RELU>
__device__ inline void gemm_body(const ushort* __restrict__ Xv,
                                 const ushort* __restrict__ Wp,
                                 ushort* __restrict__ Y,
                                 ushort* xs, ushort* wsh,
                                 int base, int tid) {
  const int rem = N_NODES - base;
  for (int i = tid; i < 2048; i += 512)
    ((uint4*)wsh)[i] = ((const uint4*)Wp)[i];

  for (int g = tid; g < 2048; g += 512) {
    int row = g >> 4;            // 0..127
    int k0 = (g & 15) << 3;
    int wt = row >> 4, ks = k0 >> 5;
    int lane = (row & 15) + (((k0 >> 3) & 3) << 4);
    uint4 v;
    if (row < rem) {
      v = *(const uint4*)(Xv + (size_t)(base + row) * 128 + k0);
    } else {
      v.x = 0; v.y = 0; v.z = 0; v.w = 0;
    }
    *(uint4*)&xs[((((wt << 2) + ks) << 6) + lane) << 3] = v;
  }
  __syncthreads();

  const int wave = tid >> 6, lane = tid & 63;
  f32x4 acc[8];
#pragma unroll
  for (int i = 0; i < 8; ++i) acc[i] = f32x4{0.f, 0.f, 0.f, 0.f};
  bf16x8 a[4];
#pragma unroll
  for (int ks = 0; ks < 4; ++ks)
    a[ks] = *(const bf16x8*)&xs[((((wave << 2) + ks) << 6) + lane) << 3];
#pragma unroll
  for (int ks = 0; ks < 4; ++ks) {
#pragma unroll
    for (int nt = 0; nt < 8; ++nt) {
      bf16x8 b = *(const bf16x8*)&wsh[((((nt << 2) + ks) << 6) + lane) << 3];
      acc[nt] = __builtin_amdgcn_mfma_f32_16x16x32_bf16(a[ks], b, acc[nt], 0, 0, 0);
    }
  }
  // C/D: col = lane&15, row = (lane>>4)*4 + reg
  const int r0 = base + wave * 16 + ((lane >> 4) << 2);
  const int c0 = lane & 15;
#pragma unroll
  for (int nt = 0; nt < 8; ++nt)
#pragma unroll
    for (int r = 0; r < 4; ++r) {
      int row = r0 + r;
      if (row < N_NODES) {
        float v = acc[nt][r];
        if (RELU) v = fmaxf(v, 0.f);
        Y[(size_t)row * 128 + (nt << 4) + c0] = f2bf(v);
      }
    }
}

// x1 = relu(a0 @ W1)
__global__ __launch_bounds__(512) void k_gemm1(const ushort* __restrict__ X,
                                               const ushort* __restrict__ Wp,
                                               ushort* __restrict__ Y) {
  __shared__ ushort xs[8 * 4 * 64 * 8];   // 32 KB
  __shared__ ushort wsh[32 * 64 * 8];     // 32 KB
  gemm_body<true>(X, Wp, Y, xs, wsh, blockIdx.x * 128, threadIdx.x);
}

// ---------------- W1 pre-pack (64 blocks) ----------------
__global__ __launch_bounds__(256) void k_wpack(const float* __restrict__ W,
                                               ushort* __restrict__ op) {
  int j = blockIdx.x * 256 + threadIdx.x;  // 0..16383
  int lane = (j >> 3) & 63;
  int e = j & 7;
  int frag = j >> 9;
  int nt = frag >> 2, ks = frag & 3;
  int c = nt * 16 + (lane & 15);
  int k = ks * 32 + (lane >> 4) * 8 + e;
  op[j] = f2bf(W[k * 128 + c]);
}

// ---------------- feat -> bf16 ----------------
__global__ __launch_bounds__(256) void k_cvt(const float* __restrict__ f,
                                             ushort* __restrict__ o) {
  int i = blockIdx.x * 256 + threadIdx.x;  // one float4 per thread; 1.6M threads
  float4 v = ((const float4*)f)[i];
  uint2 p;
  p.x = (uint)f2bf(v.x) | ((uint)f2bf(v.y) << 16);
  p.y = (uint)f2bf(v.z) | ((uint)f2bf(v.w) << 16);
  ((uint2*)o)[i] = p;
}

// ---------------- phase-1 radix edge scatter (line-padded counters) ----------------
__global__ __launch_bounds__(256) void k_scat(const int* __restrict__ esrc,
                                              const int* __restrict__ edst,
                                              int* __restrict__ cnt8,
                                              uint* __restrict__ ebuf) {
  uint xcc;
  asm volatile("s_getreg_b32 %0, hwreg(HW_REG_XCC_ID)" : "=s"(xcc));
  const int x = (int)(xcc & 7);
  for (int e = blockIdx.x * 256 + threadIdx.x; e < N_EDGES; e += gridDim.x * 256) {
    int d = edst[e];
    int bk = d >> 7;
    int dloc = d & 127;
    int p = atomicAdd(&cnt8[((bk << 3) + x) * CPAD], 1);
    if (p < ECAP)
      ebuf[(((size_t)bk << 3) + x) * ECAP + p] = (uint)esrc[e] | ((uint)dloc << 16);
  }
}

// ---------------- phase 2: per-bucket slot-CSR assembly in LDS ----------------
__global__ __launch_bounds__(256) void k_csr(const uint* __restrict__ ebuf,
                                             const int* __restrict__ cnt8,
                                             ushort* __restrict__ csr16,
                                             int* __restrict__ cnt) {
  __shared__ ushort csr_l[4096];
  __shared__ int cntL[128], off[128], cur[128];
  __shared__ int len8[8];
  const int b = blockIdx.x, tid = threadIdx.x;
  const int n0 = b << 7;
  const int nmax = min(128, N_NODES - n0);
  if (tid < 8) len8[tid] = min(cnt8[((b << 3) + tid) * CPAD], ECAP);
  for (int i = tid; i < 128; i += 256) { cntL[i] = 0; cur[i] = 0; }
  __syncthreads();
#pragma unroll
  for (int x = 0; x < 8; ++x) {
    const uint* s = ebuf + (((size_t)b << 3) + x) * ECAP;
    for (int i = tid; i < len8[x]; i += 256)
      atomicAdd(&cntL[s[i] >> 16], 1);
  }
  __syncthreads();
  if (tid == 0) {
    int o = 0;
    for (int n = 0; n < 128; ++n) { off[n] = o; o += min(cntL[n], SLOT); }
  }
  __syncthreads();
#pragma unroll
  for (int x = 0; x < 8; ++x) {
    const uint* s = ebuf + (((size_t)b << 3) + x) * ECAP;
    for (int i = tid; i < len8[x]; i += 256) {
      uint u = s[i];
      int dl = u >> 16;
      int p = atomicAdd(&cur[dl], 1);
      if (p < SLOT) csr_l[off[dl] + p] = (ushort)(u & 0xffffu);
    }
  }
  __syncthreads();
  for (int n = tid; n < nmax; n += 256) cnt[n0 + n] = min(cntL[n], SLOT);
  uint* outp = (uint*)csr16 + ((size_t)n0 << 5);
  const int tot = nmax << 5;
  for (int j = tid; j < tot; j += 256) {
    int n = j >> 5, k = (j & 31) << 1;
    int c = min(cntL[n], SLOT);
    uint lo = (k < c) ? (uint)csr_l[off[n] + k] : 0u;
    uint hi = (k + 1 < c) ? (uint)csr_l[off[n] + k + 1] : 0u;
    outp[((size_t)n << 5) + (j & 31)] = lo | (hi << 16);
  }
}

// ---------------- quarter-wave gather: 16 lanes x uint4 = one 256B row ----------------
__device__ inline void unpack_add(uint4 u, float4& a0, float4& a1) {
  a0.x += bf2f_lo(u.x); a0.y += bf2f_hi(u.x);
  a0.z += bf2f_lo(u.y); a0.w += bf2f_hi(u.y);
  a1.x += bf2f_lo(u.z); a1.y += bf2f_hi(u.z);
  a1.z += bf2f_lo(u.w); a1.w += bf2f_hi(u.w);
}

__device__ inline void gather_sum(const uint4* __restrict__ Hv,
                                  const ushort* __restrict__ nb,
                                  int deg, int q, float4& a0, float4& a1) {
  int e = 0;
  for (; e + 8 <= deg; e += 8) {
    uint4 iv = *(const uint4*)(nb + e);
    uint4 u0 = Hv[(size_t)(iv.x & 0xffffu) * 16 + q];
    uint4 u1 = Hv[(size_t)(iv.x >> 16) * 16 + q];
    uint4 u2 = Hv[(size_t)(iv.y & 0xffffu) * 16 + q];
    uint4 u3 = Hv[(size_t)(iv.y >> 16) * 16 + q];
    uint4 u4 = Hv[(size_t)(iv.z & 0xffffu) * 16 + q];
    uint4 u5 = Hv[(size_t)(iv.z >> 16) * 16 + q];
    uint4 u6 = Hv[(size_t)(iv.w & 0xffffu) * 16 + q];
    uint4 u7 = Hv[(size_t)(iv.w >> 16) * 16 + q];
    unpack_add(u0, a0, a1); unpack_add(u1, a0, a1);
    unpack_add(u2, a0, a1); unpack_add(u3, a0, a1);
    unpack_add(u4, a0, a1); unpack_add(u5, a0, a1);
    unpack_add(u6, a0, a1); unpack_add(u7, a0, a1);
  }
  if (e + 4 <= deg) {
    uint2 iv = *(const uint2*)(nb + e);
    uint4 u0 = Hv[(size_t)(iv.x & 0xffffu) * 16 + q];
    uint4 u1 = Hv[(size_t)(iv.x >> 16) * 16 + q];
    uint4 u2 = Hv[(size_t)(iv.y & 0xffffu) * 16 + q];
    uint4 u3 = Hv[(size_t)(iv.y >> 16) * 16 + q];
    unpack_add(u0, a0, a1); unpack_add(u1, a0, a1);
    unpack_add(u2, a0, a1); unpack_add(u3, a0, a1);
    e += 4;
  }
  for (; e < deg; ++e) {
    uint4 u = Hv[(size_t)nb[e] * 16 + q];
    unpack_add(u, a0, a1);
  }
}

// ---------------- agg0: a0 = (fb + gather(fb))/deg, bf16 out (NO relu) --------------
__global__ __launch_bounds__(256) void k_agg0(const ushort* __restrict__ H,
                                              const ushort* __restrict__ csr16,
                                              const int* __restrict__ cnt,
                                              ushort* __restrict__ Out) {
  const int q = threadIdx.x & 15;
  const int node = blockIdx.x * 16 + (threadIdx.x >> 4);  // 50000 = 3125*16 exact
  const int deg = min(cnt[node], SLOT);
  const ushort* nb = csr16 + (size_t)node * SLOT;
  const uint4* __restrict__ Hv = (const uint4*)H;
  float4 a0 = {0.f, 0.f, 0.f, 0.f}, a1 = {0.f, 0.f, 0.f, 0.f};
  gather_sum(Hv, nb, deg, q, a0, a1);
  uint4 uh = Hv[(size_t)node * 16 + q];
  float inv = 1.0f / (float)(deg + 1);
  float v0 = (bf2f_lo(uh.x) + a0.x) * inv;
  float v1 = (bf2f_hi(uh.x) + a0.y) * inv;
  float v2 = (bf2f_lo(uh.y) + a0.z) * inv;
  float v3 = (bf2f_hi(uh.y) + a0.w) * inv;
  float v4 = (bf2f_lo(uh.z) + a1.x) * inv;
  float v5 = (bf2f_hi(uh.z) + a1.y) * inv;
  float v6 = (bf2f_lo(uh.w) + a1.z) * inv;
  float v7 = (bf2f_hi(uh.w) + a1.w) * inv;
  uint4 ov;
  ov.x = (uint)f2bf(v0) | ((uint)f2bf(v1) << 16);
  ov.y = (uint)f2bf(v2) | ((uint)f2bf(v3) << 16);
  ov.z = (uint)f2bf(v4) | ((uint)f2bf(v5) << 16);
  ov.w = (uint)f2bf(v6) | ((uint)f2bf(v7) << 16);
  ((uint4*)Out)[(size_t)node * 16 + q] = ov;
}

// ---------------- fused agg2 + per-graph readout (a2 in fp32; x2 never formed) -------
__global__ __launch_bounds__(256) void k_agg_ro(const ushort* __restrict__ H,
                                                const ushort* __restrict__ csr16,
                                                const int* __restrict__ cnt,
                                                const int* __restrict__ gid,
                                                float* __restrict__ gsum,
                                                float* __restrict__ gcnt) {
  __shared__ float rows[16][128];
  __shared__ int gids[16];
  const int q = threadIdx.x & 15;
  const int slot = threadIdx.x >> 4;
  const int node = blockIdx.x * 16 + slot;  // exact
  const int deg = min(cnt[node], SLOT);
  const ushort* nb = csr16 + (size_t)node * SLOT;
  const uint4* __restrict__ Hv = (const uint4*)H;
  float4 a0 = {0.f, 0.f, 0.f, 0.f}, a1 = {0.f, 0.f, 0.f, 0.f};
  gather_sum(Hv, nb, deg, q, a0, a1);
  uint4 uh = Hv[(size_t)node * 16 + q];
  float inv = 1.0f / (float)(deg + 1);
  float4 r0, r1;
  r0.x = (bf2f_lo(uh.x) + a0.x) * inv;
  r0.y = (bf2f_hi(uh.x) + a0.y) * inv;
  r0.z = (bf2f_lo(uh.y) + a0.z) * inv;
  r0.w = (bf2f_hi(uh.y) + a0.w) * inv;
  r1.x = (bf2f_lo(uh.z) + a1.x) * inv;
  r1.y = (bf2f_hi(uh.z) + a1.y) * inv;
  r1.z = (bf2f_lo(uh.w) + a1.z) * inv;
  r1.w = (bf2f_hi(uh.w) + a1.w) * inv;
  *(float4*)&rows[slot][q * 8] = r0;
  *(float4*)&rows[slot][q * 8 + 4] = r1;
  if (q == 0) gids[slot] = gid[node];
  __syncthreads();
  const int t = threadIdx.x;
  if (t < 128) {
    float acc = rows[0][t];
    int g = gids[0];
#pragma unroll
    for (int r = 1; r < 16; ++r) {
      int gr = gids[r];
      if (gr != g) {
        atomicAdd(&gsum[g * 128 + t], acc);
        acc = 0.f;
        g = gr;
      }
      acc += rows[r][t];
    }
    atomicAdd(&gsum[g * 128 + t], acc);
  } else if (t == 128) {
    float c = 1.f;
    int g = gids[0];
#pragma unroll
    for (int r = 1; r < 16; ++r) {
      int gr = gids[r];
      if (gr != g) {
        atomicAdd(&gcnt[g], c);
        c = 0.f;
        g = gr;
      }
      c += 1.f;
    }
    atomicAdd(&gcnt[g], c);
  }
}

// ---------------- head: gmean -> @W2 (fp32) -> @mlp_w + b -> log_softmax -------------
// gmean(x2) = gmean(a2) @ W2, so W2 is applied to the 512x128 mean matrix only.
__global__ __launch_bounds__(128) void k_mlp2(const float* __restrict__ gsum,
                                              const float* __restrict__ gcnt,
                                              const float* __restrict__ W2,
                                              const float* __restrict__ Wm,
                                              const float* __restrict__ bm,
                                              float* __restrict__ out) {
  __shared__ float m[128];
  __shared__ float h[128];
  __shared__ float lg[NCLASS];
  const int g = blockIdx.x;
  const int t = threadIdx.x;
  float c = fmaxf(gcnt[g], 1.0f);
  m[t] = gsum[g * 128 + t] / c;
  __syncthreads();
  float s = 0.f;
#pragma unroll
  for (int k = 0; k < 128; ++k) s += m[k] * W2[k * 128 + t];
  h[t] = s;
  __syncthreads();
  if (t < NCLASS) {
    float l = bm[t];
#pragma unroll
    for (int k = 0; k < 128; ++k) l += h[k] * Wm[k * NCLASS + t];
    lg[t] = l;
  }
  __syncthreads();
  if (t < NCLASS) {
    float mx = lg[0];
#pragma unroll
    for (int i = 1; i < NCLASS; ++i) mx = fmaxf(mx, lg[i]);
    float sum = 0.f;
#pragma unroll
    for (int i = 0; i < NCLASS; ++i) sum += expf(lg[i] - mx);
    out[g * NCLASS + t] = lg[t] - mx - logf(sum);
  }
}

extern "C" void kernel_launch(void* const* d_in, const int* in_sizes, int n_in,
                              void* d_out, int out_size, void* d_ws, size_t ws_size,
                              hipStream_t stream) {
  const float* feat = (const float*)d_in[0];
  const float* W1   = (const float*)d_in[1];
  const float* W2   = (const float*)d_in[2];
  const float* Wm   = (const float*)d_in[3];
  const float* bm   = (const float*)d_in[4];
  const int* esrc   = (const int*)d_in[5];
  const int* edst   = (const int*)d_in[6];
  const int* gid    = (const int*)d_in[7];
  float* out = (float*)d_out;

  // workspace layout:
  // ints:   cnt8[NBUK*8*CPAD] | cnt[50048]
  // uint:   ebuf[NBUK*8*ECAP]
  // ushort: csr16[50048*64] | wp1[16384] | bufA[6.4M] | bufB[6.4M]
  // float:  gsum[512*128] | gcnt[512]
  int* cnt8     = (int*)d_ws;
  int* cnt      = cnt8 + NBUK * 8 * CPAD;
  uint* ebuf    = (uint*)(cnt + 50048);
  ushort* csr16 = (ushort*)(ebuf + (size_t)NBUK * 8 * ECAP);
  ushort* wp1   = csr16 + (size_t)50048 * SLOT;
  ushort* bufA  = wp1 + 16384;                      // fb, then x1
  ushort* bufB  = bufA + (size_t)N_NODES * NHID;    // a0
  float* gsum   = (float*)(bufB + (size_t)N_NODES * NHID);
  float* gcnt   = gsum + NUM_GRAPHS * NHID;

  hipMemsetAsync(cnt8, 0, (size_t)NBUK * 8 * CPAD * sizeof(int), stream);
  hipMemsetAsync(gsum, 0, (size_t)(NUM_GRAPHS * NHID + 512) * sizeof(float), stream);

  k_wpack<<<64, 256, 0, stream>>>(W1, wp1);
  k_cvt<<<(N_NODES * NHID / 4 + 255) / 256, 256, 0, stream>>>(feat, bufA);  // fb
  k_scat<<<1024, 256, 0, stream>>>(esrc, edst, cnt8, ebuf);
  k_csr<<<NBUK, 256, 0, stream>>>(ebuf, cnt8, csr16, cnt);

  // a0 = agg(fb) -> bufB
  k_agg0<<<N_NODES / 16, 256, 0, stream>>>(bufA, csr16, cnt, bufB);
  // x1 = relu(a0 @ W1) -> bufA
  k_gemm1<<<GEMM_BLOCKS, 512, 0, stream>>>(bufB, wp1, bufA);
  // gsum/gcnt = per-graph sums of a2 = agg(x1)  (x2 never materialized)
  k_agg_ro<<<N_NODES / 16, 256, 0, stream>>>(bufA, csr16, cnt, gid, gsum, gcnt);
  // head: gmean -> @W2 -> @mlp_w+b -> log_softmax
  k_mlp2<<<NUM_GRAPHS, 128, 0, stream>>>(gsum, gcnt, W2, Wm, bm, out);
}

// Round 15
// 218.940 us; speedup vs baseline: 1.2180x; 1.0302x over previous
//
#include <hip/hip_runtime.h>

#define N_NODES 50000
#define N_EDGES 800000
#define NFEAT 128
#define NHID 128
#define NCLASS 10
#define NUM_GRAPHS 512
#define GEMM_BLOCKS 391    // ceil(50000/128), 128-row tiles
#define SLOT 64            // per-node CSR capacity; 64*2B = one 128B line
#define NBUK 391           // ceil(50000/128) radix buckets (bk = d>>7)
#define ECAP 512           // per-(bucket,xcd) stream capacity
#define CPAD 32            // ints per counter: one 128B line each

// k_prep grid partition: [scat | wpack | cvt]
#define P_SCAT 1024
#define P_WPACK 64
#define P_CVT 6250         // 1.6M float4 / 256
#define P_GRID (P_SCAT + P_WPACK + P_CVT)

typedef __attribute__((ext_vector_type(8))) short bf16x8;
typedef __attribute__((ext_vector_type(4))) float f32x4;

__device__ inline ushort f2bf(float f) {
  union { float f; uint u; } c; c.f = f;
  return (ushort)((c.u + 0x7fffu + ((c.u >> 16) & 1u)) >> 16);
}
__device__ inline float bf2f_lo(uint u) { union { uint u; float f; } c; c.u = u << 16; return c.f; }
__device__ inline float bf2f_hi(uint u) { union { uint u; float f; } c; c.u = u & 0xffff0000u; return c.f; }

// ---------------- MFMA GEMM: 128-row tile, 512 threads, bf16 in, fused ReLU ---------
template <bool RELU>
__device__ inline void gemm_body(const ushort* __restrict__ Xv,
                                 const ushort* __restrict__ Wp,
                                 ushort* __restrict__ Y,
                                 ushort* xs, ushort* wsh,
                                 int base, int tid) {
  const int rem = N_NODES - base;
  for (int i = tid; i < 2048; i += 512)
    ((uint4*)wsh)[i] = ((const uint4*)Wp)[i];

  for (int g = tid; g < 2048; g += 512) {
    int row = g >> 4;            // 0..127
    int k0 = (g & 15) << 3;
    int wt = row >> 4, ks = k0 >> 5;
    int lane = (row & 15) + (((k0 >> 3) & 3) << 4);
    uint4 v;
    if (row < rem) {
      v = *(const uint4*)(Xv + (size_t)(base + row) * 128 + k0);
    } else {
      v.x = 0; v.y = 0; v.z = 0; v.w = 0;
    }
    *(uint4*)&xs[((((wt << 2) + ks) << 6) + lane) << 3] = v;
  }
  __syncthreads();

  const int wave = tid >> 6, lane = tid & 63;
  f32x4 acc[8];
#pragma unroll
  for (int i = 0; i < 8; ++i) acc[i] = f32x4{0.f, 0.f, 0.f, 0.f};
  bf16x8 a[4];
#pragma unroll
  for (int ks = 0; ks < 4; ++ks)
    a[ks] = *(const bf16x8*)&xs[((((wave << 2) + ks) << 6) + lane) << 3];
#pragma unroll
  for (int ks = 0; ks < 4; ++ks) {
#pragma unroll
    for (int nt = 0; nt < 8; ++nt) {
      bf16x8 b = *(const bf16x8*)&wsh[((((nt << 2) + ks) << 6) + lane) << 3];
      acc[nt] = __builtin_amdgcn_mfma_f32_16x16x32_bf16(a[ks], b, acc[nt], 0, 0, 0);
    }
  }
  // C/D: col = lane&15, row = (lane>>4)*4 + reg
  const int r0 = base + wave * 16 + ((lane >> 4) << 2);
  const int c0 = lane & 15;
#pragma unroll
  for (int nt = 0; nt < 8; ++nt)
#pragma unroll
    for (int r = 0; r < 4; ++r) {
      int row = r0 + r;
      if (row < N_NODES) {
        float v = acc[nt][r];
        if (RELU) v = fmaxf(v, 0.f);
        Y[(size_t)row * 128 + (nt << 4) + c0] = f2bf(v);
      }
    }
}

// x1 = relu(a0 @ W1)
__global__ __launch_bounds__(512) void k_gemm1(const ushort* __restrict__ X,
                                               const ushort* __restrict__ Wp,
                                               ushort* __restrict__ Y) {
  __shared__ ushort xs[8 * 4 * 64 * 8];   // 32 KB
  __shared__ ushort wsh[32 * 64 * 8];     // 32 KB
  gemm_body<true>(X, Wp, Y, xs, wsh, blockIdx.x * 128, threadIdx.x);
}

// ---------------- merged prep: [scat | wpack(W1) | cvt(feat->bf16)] ----------------
// All parts LDS-free and independent; scat blocks first (long pole).
__global__ __launch_bounds__(256) void k_prep(const int* __restrict__ esrc,
                                              const int* __restrict__ edst,
                                              int* __restrict__ cnt8,
                                              uint* __restrict__ ebuf,
                                              const float* __restrict__ W1,
                                              ushort* __restrict__ wp1,
                                              const float* __restrict__ feat,
                                              ushort* __restrict__ fb) {
  const int b = blockIdx.x;
  const int tid = threadIdx.x;
  if (b < P_SCAT) {
    // phase-1 radix edge scatter; line-padded counters (per-line atomic serialization)
    uint xcc;
    asm volatile("s_getreg_b32 %0, hwreg(HW_REG_XCC_ID)" : "=s"(xcc));
    const int x = (int)(xcc & 7);
    for (int e = b * 256 + tid; e < N_EDGES; e += P_SCAT * 256) {
      int d = edst[e];
      int bk = d >> 7;
      int dloc = d & 127;
      int p = atomicAdd(&cnt8[((bk << 3) + x) * CPAD], 1);
      if (p < ECAP)
        ebuf[(((size_t)bk << 3) + x) * ECAP + p] = (uint)esrc[e] | ((uint)dloc << 16);
    }
  } else if (b < P_SCAT + P_WPACK) {
    int j = (b - P_SCAT) * 256 + tid;  // 0..16383
    int lane = (j >> 3) & 63;
    int e = j & 7;
    int frag = j >> 9;
    int nt = frag >> 2, ks = frag & 3;
    int c = nt * 16 + (lane & 15);
    int k = ks * 32 + (lane >> 4) * 8 + e;
    wp1[j] = f2bf(W1[k * 128 + c]);
  } else {
    int i = (b - P_SCAT - P_WPACK) * 256 + tid;  // one float4 per thread
    float4 v = ((const float4*)feat)[i];
    uint2 p;
    p.x = (uint)f2bf(v.x) | ((uint)f2bf(v.y) << 16);
    p.y = (uint)f2bf(v.z) | ((uint)f2bf(v.w) << 16);
    ((uint2*)fb)[i] = p;
  }
}

// ---------------- phase 2: per-bucket slot-CSR assembly, rows CHUNK-SORTED by src ----
// Sorting each node's row by src>>13 (7 chunks x 2MB of H) makes the agg kernels'
// gather walk ascending address bands: the GPU-wide instantaneous working set
// becomes ~2-4MB (L2-fit) instead of 12.8MB -> L2 hits instead of L3/HBM.
__global__ __launch_bounds__(256) void k_csr(const uint* __restrict__ ebuf,
                                             const int* __restrict__ cnt8,
                                             ushort* __restrict__ csr16,
                                             int* __restrict__ cnt) {
  __shared__ ushort csr_l[4096];
  __shared__ int cntL[128], off[128];
  __shared__ int cofs[128 * 8];   // per-node per-chunk offsets (then cursors share)
  __shared__ int cur8[128 * 8];
  __shared__ int len8[8];
  const int b = blockIdx.x, tid = threadIdx.x;
  const int n0 = b << 7;
  const int nmax = min(128, N_NODES - n0);
  if (tid < 8) len8[tid] = min(cnt8[((b << 3) + tid) * CPAD], ECAP);
  for (int i = tid; i < 128; i += 256) cntL[i] = 0;
  for (int i = tid; i < 1024; i += 256) { cofs[i] = 0; cur8[i] = 0; }
  __syncthreads();
  // pass 1: count per node and per (node, chunk)
#pragma unroll
  for (int x = 0; x < 8; ++x) {
    const uint* s = ebuf + (((size_t)b << 3) + x) * ECAP;
    for (int i = tid; i < len8[x]; i += 256) {
      uint u = s[i];
      int dl = u >> 16;
      int ck = (u & 0xffffu) >> 13;  // 0..6
      atomicAdd(&cntL[dl], 1);
      atomicAdd(&cofs[(dl << 3) + ck], 1);
    }
  }
  __syncthreads();
  if (tid == 0) {
    int o = 0;
    for (int n = 0; n < 128; ++n) { off[n] = o; o += min(cntL[n], SLOT); }
  }
  if (tid < 128) {  // per-node chunk prefix (counts -> offsets)
    int s = 0;
#pragma unroll
    for (int k = 0; k < 8; ++k) {
      int c = cofs[(tid << 3) + k];
      cofs[(tid << 3) + k] = s;
      s += c;
    }
  }
  __syncthreads();
  // pass 2: scatter into chunk-sorted position
#pragma unroll
  for (int x = 0; x < 8; ++x) {
    const uint* s = ebuf + (((size_t)b << 3) + x) * ECAP;
    for (int i = tid; i < len8[x]; i += 256) {
      uint u = s[i];
      int dl = u >> 16;
      int ck = (u & 0xffffu) >> 13;
      int p = atomicAdd(&cur8[(dl << 3) + ck], 1);
      int idx = cofs[(dl << 3) + ck] + p;
      if (idx < SLOT) csr_l[off[dl] + idx] = (ushort)(u & 0xffffu);
    }
  }
  __syncthreads();
  for (int n = tid; n < nmax; n += 256) cnt[n0 + n] = min(cntL[n], SLOT);
  uint* outp = (uint*)csr16 + ((size_t)n0 << 5);
  const int tot = nmax << 5;
  for (int j = tid; j < tot; j += 256) {
    int n = j >> 5, k = (j & 31) << 1;
    int c = min(cntL[n], SLOT);
    uint lo = (k < c) ? (uint)csr_l[off[n] + k] : 0u;
    uint hi = (k + 1 < c) ? (uint)csr_l[off[n] + k + 1] : 0u;
    outp[((size_t)n << 5) + (j & 31)] = lo | (hi << 16);
  }
}

// ---------------- quarter-wave gather: 16 lanes x uint4 = one 256B row ----------------
__device__ inline void unpack_add(uint4 u, float4& a0, float4& a1) {
  a0.x += bf2f_lo(u.x); a0.y += bf2f_hi(u.x);
  a0.z += bf2f_lo(u.y); a0.w += bf2f_hi(u.y);
  a1.x += bf2f_lo(u.z); a1.y += bf2f_hi(u.z);
  a1.z += bf2f_lo(u.w); a1.w += bf2f_hi(u.w);
}

__device__ inline void gather_sum(const uint4* __restrict__ Hv,
                                  const ushort* __restrict__ nb,
                                  int deg, int q, float4& a0, float4& a1) {
  int e = 0;
  for (; e + 8 <= deg; e += 8) {
    uint4 iv = *(const uint4*)(nb + e);
    uint4 u0 = Hv[(size_t)(iv.x & 0xffffu) * 16 + q];
    uint4 u1 = Hv[(size_t)(iv.x >> 16) * 16 + q];
    uint4 u2 = Hv[(size_t)(iv.y & 0xffffu) * 16 + q];
    uint4 u3 = Hv[(size_t)(iv.y >> 16) * 16 + q];
    uint4 u4 = Hv[(size_t)(iv.z & 0xffffu) * 16 + q];
    uint4 u5 = Hv[(size_t)(iv.z >> 16) * 16 + q];
    uint4 u6 = Hv[(size_t)(iv.w & 0xffffu) * 16 + q];
    uint4 u7 = Hv[(size_t)(iv.w >> 16) * 16 + q];
    unpack_add(u0, a0, a1); unpack_add(u1, a0, a1);
    unpack_add(u2, a0, a1); unpack_add(u3, a0, a1);
    unpack_add(u4, a0, a1); unpack_add(u5, a0, a1);
    unpack_add(u6, a0, a1); unpack_add(u7, a0, a1);
  }
  if (e + 4 <= deg) {
    uint2 iv = *(const uint2*)(nb + e);
    uint4 u0 = Hv[(size_t)(iv.x & 0xffffu) * 16 + q];
    uint4 u1 = Hv[(size_t)(iv.x >> 16) * 16 + q];
    uint4 u2 = Hv[(size_t)(iv.y & 0xffffu) * 16 + q];
    uint4 u3 = Hv[(size_t)(iv.y >> 16) * 16 + q];
    unpack_add(u0, a0, a1); unpack_add(u1, a0, a1);
    unpack_add(u2, a0, a1); unpack_add(u3, a0, a1);
    e += 4;
  }
  for (; e < deg; ++e) {
    uint4 u = Hv[(size_t)nb[e] * 16 + q];
    unpack_add(u, a0, a1);
  }
}

// ---------------- agg0: a0 = (fb + gather(fb))/deg, bf16 out (NO relu) --------------
__global__ __launch_bounds__(256) void k_agg0(const ushort* __restrict__ H,
                                              const ushort* __restrict__ csr16,
                                              const int* __restrict__ cnt,
                                              ushort* __restrict__ Out) {
  const int q = threadIdx.x & 15;
  const int node = blockIdx.x * 16 + (threadIdx.x >> 4);  // 50000 = 3125*16 exact
  const int deg = min(cnt[node], SLOT);
  const ushort* nb = csr16 + (size_t)node * SLOT;
  const uint4* __restrict__ Hv = (const uint4*)H;
  float4 a0 = {0.f, 0.f, 0.f, 0.f}, a1 = {0.f, 0.f, 0.f, 0.f};
  gather_sum(Hv, nb, deg, q, a0, a1);
  uint4 uh = Hv[(size_t)node * 16 + q];
  float inv = 1.0f / (float)(deg + 1);
  float v0 = (bf2f_lo(uh.x) + a0.x) * inv;
  float v1 = (bf2f_hi(uh.x) + a0.y) * inv;
  float v2 = (bf2f_lo(uh.y) + a0.z) * inv;
  float v3 = (bf2f_hi(uh.y) + a0.w) * inv;
  float v4 = (bf2f_lo(uh.z) + a1.x) * inv;
  float v5 = (bf2f_hi(uh.z) + a1.y) * inv;
  float v6 = (bf2f_lo(uh.w) + a1.z) * inv;
  float v7 = (bf2f_hi(uh.w) + a1.w) * inv;
  uint4 ov;
  ov.x = (uint)f2bf(v0) | ((uint)f2bf(v1) << 16);
  ov.y = (uint)f2bf(v2) | ((uint)f2bf(v3) << 16);
  ov.z = (uint)f2bf(v4) | ((uint)f2bf(v5) << 16);
  ov.w = (uint)f2bf(v6) | ((uint)f2bf(v7) << 16);
  ((uint4*)Out)[(size_t)node * 16 + q] = ov;
}

// ---------------- fused agg2 + per-graph readout (a2 in fp32; x2 never formed) -------
__global__ __launch_bounds__(256) void k_agg_ro(const ushort* __restrict__ H,
                                                const ushort* __restrict__ csr16,
                                                const int* __restrict__ cnt,
                                                const int* __restrict__ gid,
                                                float* __restrict__ gsum,
                                                float* __restrict__ gcnt) {
  __shared__ float rows[16][128];
  __shared__ int gids[16];
  const int q = threadIdx.x & 15;
  const int slot = threadIdx.x >> 4;
  const int node = blockIdx.x * 16 + slot;  // exact
  const int deg = min(cnt[node], SLOT);
  const ushort* nb = csr16 + (size_t)node * SLOT;
  const uint4* __restrict__ Hv = (const uint4*)H;
  float4 a0 = {0.f, 0.f, 0.f, 0.f}, a1 = {0.f, 0.f, 0.f, 0.f};
  gather_sum(Hv, nb, deg, q, a0, a1);
  uint4 uh = Hv[(size_t)node * 16 + q];
  float inv = 1.0f / (float)(deg + 1);
  float4 r0, r1;
  r0.x = (bf2f_lo(uh.x) + a0.x) * inv;
  r0.y = (bf2f_hi(uh.x) + a0.y) * inv;
  r0.z = (bf2f_lo(uh.y) + a0.z) * inv;
  r0.w = (bf2f_hi(uh.y) + a0.w) * inv;
  r1.x = (bf2f_lo(uh.z) + a1.x) * inv;
  r1.y = (bf2f_hi(uh.z) + a1.y) * inv;
  r1.z = (bf2f_lo(uh.w) + a1.z) * inv;
  r1.w = (bf2f_hi(uh.w) + a1.w) * inv;
  *(float4*)&rows[slot][q * 8] = r0;
  *(float4*)&rows[slot][q * 8 + 4] = r1;
  if (q == 0) gids[slot] = gid[node];
  __syncthreads();
  const int t = threadIdx.x;
  if (t < 128) {
    float acc = rows[0][t];
    int g = gids[0];
#pragma unroll
    for (int r = 1; r < 16; ++r) {
      int gr = gids[r];
      if (gr != g) {
        atomicAdd(&gsum[g * 128 + t], acc);
        acc = 0.f;
        g = gr;
      }
      acc += rows[r][t];
    }
    atomicAdd(&gsum[g * 128 + t], acc);
  } else if (t == 128) {
    float c = 1.f;
    int g = gids[0];
#pragma unroll
    for (int r = 1; r < 16; ++r) {
      int gr = gids[r];
      if (gr != g) {
        atomicAdd(&gcnt[g], c);
        c = 0.f;
        g = gr;
      }
      c += 1.f;
    }
    atomicAdd(&gcnt[g], c);
  }
}

// ---------------- head: gmean -> @W2 (fp32) -> @mlp_w + b -> log_softmax -------------
__global__ __launch_bounds__(128) void k_mlp2(const float* __restrict__ gsum,
                                              const float* __restrict__ gcnt,
                                              const float* __restrict__ W2,
                                              const float* __restrict__ Wm,
                                              const float* __restrict__ bm,
                                              float* __restrict__ out) {
  __shared__ float m[128];
  __shared__ float h[128];
  __shared__ float lg[NCLASS];
  const int g = blockIdx.x;
  const int t = threadIdx.x;
  float c = fmaxf(gcnt[g], 1.0f);
  m[t] = gsum[g * 128 + t] / c;
  __syncthreads();
  float s = 0.f;
#pragma unroll
  for (int k = 0; k < 128; ++k) s += m[k] * W2[k * 128 + t];
  h[t] = s;
  __syncthreads();
  if (t < NCLASS) {
    float l = bm[t];
#pragma unroll
    for (int k = 0; k < 128; ++k) l += h[k] * Wm[k * NCLASS + t];
    lg[t] = l;
  }
  __syncthreads();
  if (t < NCLASS) {
    float mx = lg[0];
#pragma unroll
    for (int i = 1; i < NCLASS; ++i) mx = fmaxf(mx, lg[i]);
    float sum = 0.f;
#pragma unroll
    for (int i = 0; i < NCLASS; ++i) sum += expf(lg[i] - mx);
    out[g * NCLASS + t] = lg[t] - mx - logf(sum);
  }
}

extern "C" void kernel_launch(void* const* d_in, const int* in_sizes, int n_in,
                              void* d_out, int out_size, void* d_ws, size_t ws_size,
                              hipStream_t stream) {
  const float* feat = (const float*)d_in[0];
  const float* W1   = (const float*)d_in[1];
  const float* W2   = (const float*)d_in[2];
  const float* Wm   = (const float*)d_in[3];
  const float* bm   = (const float*)d_in[4];
  const int* esrc   = (const int*)d_in[5];
  const int* edst   = (const int*)d_in[6];
  const int* gid    = (const int*)d_in[7];
  float* out = (float*)d_out;

  // workspace layout:
  // ints:   cnt8[NBUK*8*CPAD] | cnt[50048]
  // uint:   ebuf[NBUK*8*ECAP]
  // ushort: csr16[50048*64] | wp1[16384] | bufA[6.4M] | bufB[6.4M]
  // float:  gsum[512*128] | gcnt[512]
  int* cnt8     = (int*)d_ws;
  int* cnt      = cnt8 + NBUK * 8 * CPAD;
  uint* ebuf    = (uint*)(cnt + 50048);
  ushort* csr16 = (ushort*)(ebuf + (size_t)NBUK * 8 * ECAP);
  ushort* wp1   = csr16 + (size_t)50048 * SLOT;
  ushort* bufA  = wp1 + 16384;                      // fb, then x1
  ushort* bufB  = bufA + (size_t)N_NODES * NHID;    // a0
  float* gsum   = (float*)(bufB + (size_t)N_NODES * NHID);
  float* gcnt   = gsum + NUM_GRAPHS * NHID;

  hipMemsetAsync(cnt8, 0, (size_t)NBUK * 8 * CPAD * sizeof(int), stream);
  hipMemsetAsync(gsum, 0, (size_t)(NUM_GRAPHS * NHID + 512) * sizeof(float), stream);

  // merged prep: edge scatter + W1 pack + feat->bf16
  k_prep<<<P_GRID, 256, 0, stream>>>(esrc, edst, cnt8, ebuf, W1, wp1, feat, bufA);
  // chunk-sorted slot-CSR
  k_csr<<<NBUK, 256, 0, stream>>>(ebuf, cnt8, csr16, cnt);

  // a0 = agg(fb) -> bufB
  k_agg0<<<N_NODES / 16, 256, 0, stream>>>(bufA, csr16, cnt, bufB);
  // x1 = relu(a0 @ W1) -> bufA
  k_gemm1<<<GEMM_BLOCKS, 512, 0, stream>>>(bufB, wp1, bufA);
  // gsum/gcnt = per-graph sums of a2 = agg(x1)
  k_agg_ro<<<N_NODES / 16, 256, 0, stream>>>(bufA, csr16, cnt, gid, gsum, gcnt);
  // head
  k_mlp2<<<NUM_GRAPHS, 128, 0, stream>>>(gsum, gcnt, W2, Wm, bm, out);
}